// Round 1
// baseline (4947.342 us; speedup 1.0000x reference)
//
#include <hip/hip_runtime.h>
#include <math.h>

#define NN 10000
#define FIN 512
#define HIDN 256
#define NC 16
static constexpr float INV_C = 1.0f / 16.0f;

// ---------------------------------------------------------------
// Generic fp32 GEMM with N fixed at 256: C[M,256] = A[M,K] @ B[K,256]
// BM=32, BN=256, BK=16; 256 threads; 4 rows x 8 cols per thread.
// Optional bias + relu on epilogue (bias/relu applied per-column).
// ---------------------------------------------------------------
template<int RELU>
__global__ __launch_bounds__(256)
void gemm_bn256(const float* __restrict__ A, const float* __restrict__ B,
                const float* __restrict__ bias, float* __restrict__ Cm,
                int M, int K)
{
    __shared__ float As[16][36];    // transposed: As[c][r], padded stride 36 (16B-aligned)
    __shared__ float Bs[16][256];
    const int t = threadIdx.x;
    const int row0 = blockIdx.x * 32;
    const int rg = t >> 5;          // 0..7 -> rows rg*4 .. +3
    const int cg = t & 31;          // 0..31 -> cols cg*8 .. +7

    float acc[4][8];
#pragma unroll
    for (int r = 0; r < 4; ++r)
#pragma unroll
        for (int c = 0; c < 8; ++c) acc[r][c] = 0.f;

    for (int kc = 0; kc < K; kc += 16) {
        // stage A tile 32x16 (transposed), 2 elems/thread
#pragma unroll
        for (int i = 0; i < 2; ++i) {
            int idx = t + i * 256;
            int r = idx >> 4, c = idx & 15;
            int gr = row0 + r;
            As[c][r] = (gr < M) ? A[(size_t)gr * K + kc + c] : 0.f;
        }
        // stage B tile 16x256, 16 elems/thread, coalesced
#pragma unroll
        for (int i = 0; i < 16; ++i) {
            Bs[i][t] = B[(size_t)(kc + i) * 256 + t];
        }
        __syncthreads();
#pragma unroll
        for (int jj = 0; jj < 16; ++jj) {
            float4 a4 = *(const float4*)&As[jj][rg * 4];
            float4 b0 = *(const float4*)&Bs[jj][cg * 8];
            float4 b1v = *(const float4*)&Bs[jj][cg * 8 + 4];
            float a[4] = {a4.x, a4.y, a4.z, a4.w};
            float b[8] = {b0.x, b0.y, b0.z, b0.w, b1v.x, b1v.y, b1v.z, b1v.w};
#pragma unroll
            for (int r = 0; r < 4; ++r)
#pragma unroll
                for (int c = 0; c < 8; ++c)
                    acc[r][c] += a[r] * b[c];
        }
        __syncthreads();
    }
#pragma unroll
    for (int r = 0; r < 4; ++r) {
        int gr = row0 + rg * 4 + r;
        if (gr < M) {
#pragma unroll
            for (int c = 0; c < 8; ++c) {
                int col = cg * 8 + c;
                float v = acc[r][c];
                if (bias) v += bias[col];
                if (RELU) v = fmaxf(v, 0.f);
                Cm[(size_t)gr * 256 + col] = v;
            }
        }
    }
}

// ---------------------------------------------------------------
// K=16-wide adjacency pass: P[s] = A[:, jrange_s] @ Mx[jrange_s, :]
// A is [NN,NN], Mx is [NN,16]. 2-way j-split over blockIdx.y.
// BM=64 rows/block; thread: 4 rows x 1 col.
// ---------------------------------------------------------------
__global__ __launch_bounds__(256)
void adj16_partial(const float* __restrict__ A, const float* __restrict__ Mx,
                   float* __restrict__ P)
{
    __shared__ float As[16][68];    // transposed [c][r], 64 rows, padded (16B-aligned stride)
    __shared__ float Ms[16][16];
    const int t = threadIdx.x;
    const int row0 = blockIdx.x * 64;
    const int s = blockIdx.y;
    const int k = t & 15;
    const int rg = t >> 4;          // 0..15 -> rows rg*4 .. +3
    // chunk range: total 625 chunks of 16 j's, split in two
    const int c0 = (625 * s) / 2;
    const int c1 = (625 * (s + 1)) / 2;

    float acc[4] = {0.f, 0.f, 0.f, 0.f};
    for (int ch = c0; ch < c1; ++ch) {
        int j0 = ch * 16;
        // stage A tile 64x16 transposed, 4 elems/thread
#pragma unroll
        for (int i = 0; i < 4; ++i) {
            int idx = t + i * 256;
            int r = idx >> 4, c = idx & 15;
            int gr = row0 + r;
            As[c][r] = (gr < NN) ? A[(size_t)gr * NN + j0 + c] : 0.f;
        }
        // stage Mx tile 16x16, 1 elem/thread (coalesced)
        Ms[t >> 4][t & 15] = Mx[(size_t)(j0 + (t >> 4)) * 16 + (t & 15)];
        __syncthreads();
#pragma unroll
        for (int jj = 0; jj < 16; ++jj) {
            float4 a4 = *(const float4*)&As[jj][rg * 4];
            float m = Ms[jj][k];
            acc[0] += a4.x * m;
            acc[1] += a4.y * m;
            acc[2] += a4.z * m;
            acc[3] += a4.w * m;
        }
        __syncthreads();
    }
#pragma unroll
    for (int r = 0; r < 4; ++r) {
        int gr = row0 + rg * 4 + r;
        if (gr < NN)
            P[(size_t)s * (NN * 16) + (size_t)gr * 16 + k] = acc[r];
    }
}

// ---------------------------------------------------------------
// hw2 = h[NN,256] @ W2[256,16]
// ---------------------------------------------------------------
__global__ __launch_bounds__(256)
void gemm_h_w2(const float* __restrict__ h, const float* __restrict__ W2,
               float* __restrict__ out)
{
    __shared__ float Ws[HIDN * 16];
    const int t = threadIdx.x;
#pragma unroll
    for (int i = 0; i < 16; ++i) Ws[t + i * 256] = W2[t + i * 256];
    __syncthreads();
    const int k = t & 15;
    const int lr = t >> 4;
    const int row = blockIdx.x * 16 + lr;
    if (row >= NN) return;
    float acc = 0.f;
    for (int m = 0; m < HIDN; ++m)
        acc += h[(size_t)row * HIDN + m] * Ws[m * 16 + k];
    out[(size_t)row * 16 + k] = acc;
}

// ---------------------------------------------------------------
// logits = P0 + P1 + b2 ; prior = softmax(logits); E = prior - 1/C; B = E
// one thread per row
// ---------------------------------------------------------------
__global__ __launch_bounds__(256)
void softmax_e(const float* __restrict__ P, const float* __restrict__ b2,
               float* __restrict__ E, float* __restrict__ B)
{
    int i = blockIdx.x * 256 + threadIdx.x;
    if (i >= NN) return;
    float l[16];
    float mx = -1e30f;
#pragma unroll
    for (int k = 0; k < 16; ++k) {
        l[k] = P[i * 16 + k] + P[NN * 16 + i * 16 + k] + b2[k];
        mx = fmaxf(mx, l[k]);
    }
    float ssum = 0.f;
#pragma unroll
    for (int k = 0; k < 16; ++k) { l[k] = __expf(l[k] - mx); ssum += l[k]; }
    float inv = 1.f / ssum;
#pragma unroll
    for (int k = 0; k < 16; ++k) {
        float e = l[k] * inv - INV_C;
        E[i * 16 + k] = e;
        B[i * 16 + k] = e;
    }
}

// ---------------------------------------------------------------
// bh = B[NN,16] @ H[16,16]
// ---------------------------------------------------------------
__global__ __launch_bounds__(256)
void bmm_h(const float* __restrict__ B, const float* __restrict__ H,
           float* __restrict__ bh)
{
    __shared__ float Hs[256];
    const int t = threadIdx.x;
    Hs[t] = H[t & 255];
    __syncthreads();
    const int k = t & 15;
    const int lr = t >> 4;
    const int row = blockIdx.x * 16 + lr;
    if (row >= NN) return;
    float acc = 0.f;
#pragma unroll
    for (int m = 0; m < 16; ++m)
        acc += B[row * 16 + m] * Hs[m * 16 + k];
    bh[row * 16 + k] = acc;
}

// ---------------------------------------------------------------
// out = E + P0 + P1 + addc
// ---------------------------------------------------------------
__global__ __launch_bounds__(256)
void combine_k(const float* __restrict__ E, const float* __restrict__ P,
               float* __restrict__ out, float addc)
{
    int idx = blockIdx.x * 256 + threadIdx.x;
    if (idx < NN * 16)
        out[idx] = E[idx] + P[idx] + P[NN * 16 + idx] + addc;
}

extern "C" void kernel_launch(void* const* d_in, const int* in_sizes, int n_in,
                              void* d_out, int out_size, void* d_ws, size_t ws_size,
                              hipStream_t stream)
{
    const float* raw_adj    = (const float*)d_in[0];
    const float* normed_adj = (const float*)d_in[1];
    const float* features   = (const float*)d_in[2];
    const float* W1 = (const float*)d_in[5];
    const float* b1 = (const float*)d_in[6];
    const float* W2 = (const float*)d_in[7];
    const float* b2 = (const float*)d_in[8];
    const float* H  = (const float*)d_in[9];
    float* out = (float*)d_out;

    float* ws  = (float*)d_ws;
    float* XW  = ws;                          // NN*256
    float* h   = XW + (size_t)NN * 256;       // NN*256
    float* hw2 = h + (size_t)NN * 256;        // NN*16
    float* P   = hw2 + (size_t)NN * 16;       // 2*NN*16
    float* E   = P + (size_t)2 * NN * 16;     // NN*16
    float* B   = E + (size_t)NN * 16;         // NN*16
    float* bh  = B + (size_t)NN * 16;         // NN*16

    // 1) XW = features @ W1
    gemm_bn256<0><<<313, 256, 0, stream>>>(features, W1, nullptr, XW, NN, FIN);
    // 2) h = relu(normed_adj @ XW + b1)
    gemm_bn256<1><<<313, 256, 0, stream>>>(normed_adj, XW, b1, h, NN, NN);
    // 3) hw2 = h @ W2
    gemm_h_w2<<<625, 256, 0, stream>>>(h, W2, hw2);
    // 4) logits partials = normed_adj @ hw2
    adj16_partial<<<dim3(157, 2), 256, 0, stream>>>(normed_adj, hw2, P);
    // 5) softmax -> E_hat, B0
    softmax_e<<<40, 256, 0, stream>>>(P, b2, E, B);
    // 6) 4 belief-propagation iterations
    for (int it = 0; it < 4; ++it) {
        bmm_h<<<625, 256, 0, stream>>>(B, H, bh);
        adj16_partial<<<dim3(157, 2), 256, 0, stream>>>(raw_adj, bh, P);
        const bool last = (it == 3);
        combine_k<<<625, 256, 0, stream>>>(E, P, last ? out : B,
                                           last ? INV_C : 0.f);
    }
}

// Round 2
// 719.836 us; speedup vs baseline: 6.8729x; 6.8729x over previous
//
#include <hip/hip_runtime.h>

#define NN 10000
#define KP 10048           // NN padded to multiple of 64
static constexpr float INV_C = 1.0f / 16.0f;

typedef __attribute__((ext_vector_type(8))) short bf16x8;
typedef __attribute__((ext_vector_type(4))) float f32x4;
typedef unsigned short u16;
typedef unsigned int u32;

__device__ __forceinline__ u16 f2b(float f) {            // RNE f32 -> bf16
    union { float f; u32 u; } v; v.f = f;
    u32 r = v.u + 0x7FFFu + ((v.u >> 16) & 1u);
    return (u16)(r >> 16);
}
__device__ __forceinline__ float b2f(u16 b) {
    union { u32 u; float f; } v; v.u = ((u32)b) << 16;
    return v.f;
}

#define AS1(p) ((__attribute__((address_space(1))) void*)(p))
#define AS3(p) ((__attribute__((address_space(3))) void*)(p))

// ---------------------------------------------------------------
// cvt_pad: fp32 [NN][NN] -> bf16 [NN][KP], zero pad cols >= NN
// grid (5, NN), 256 thr; thread handles 8 elems
// ---------------------------------------------------------------
__global__ __launch_bounds__(256)
void cvt_pad(const float* __restrict__ src, u16* __restrict__ dst)
{
    int c8 = blockIdx.x * 256 + threadIdx.x;       // 0..1279
    if (c8 >= KP / 8) return;
    int row = blockIdx.y;
    bf16x8 o;
    if (c8 < NN / 8) {
        const float4* s4 = (const float4*)(src + (size_t)row * NN + c8 * 8);
        float4 a = s4[0], b = s4[1];
        o[0]=f2b(a.x); o[1]=f2b(a.y); o[2]=f2b(a.z); o[3]=f2b(a.w);
        o[4]=f2b(b.x); o[5]=f2b(b.y); o[6]=f2b(b.z); o[7]=f2b(b.w);
    } else {
        o = bf16x8{0,0,0,0,0,0,0,0};
    }
    *(bf16x8*)(dst + (size_t)row * KP + c8 * 8) = o;
}

// ---------------------------------------------------------------
// cvt_feat: fp32 [NN][512] -> bf16 [NN][512]; grid 2500 exact
// ---------------------------------------------------------------
__global__ __launch_bounds__(256)
void cvt_feat(const float* __restrict__ src, u16* __restrict__ dst)
{
    int c = blockIdx.x * 256 + threadIdx.x;    // 640000 chunks of 8
    size_t base = (size_t)c * 8;
    const float4* s4 = (const float4*)(src + base);
    float4 a = s4[0], b = s4[1];
    bf16x8 o;
    o[0]=f2b(a.x); o[1]=f2b(a.y); o[2]=f2b(a.z); o[3]=f2b(a.w);
    o[4]=f2b(b.x); o[5]=f2b(b.y); o[6]=f2b(b.z); o[7]=f2b(b.w);
    *(bf16x8*)(dst + base) = o;
}

// ---------------------------------------------------------------
// w12t: W1T fp32 [256][512] <- W1 [512][256];  W2T bf16 [16][256] <- W2 [256][16]
// grid 528
// ---------------------------------------------------------------
__global__ __launch_bounds__(256)
void w12t(const float* __restrict__ W1, const float* __restrict__ W2,
          float* __restrict__ W1T, u16* __restrict__ W2T)
{
    int bid = blockIdx.x, t = threadIdx.x;
    if (bid < 512) {
        int idx = bid * 256 + t;           // n*512 + k
        int n = idx >> 9, k = idx & 511;
        W1T[idx] = W1[(size_t)k * 256 + n];
    } else {
        int idx = (bid - 512) * 256 + t;   // 4096 elems: n_*256 + k_
        if (idx < 4096) {
            int n_ = idx >> 8, k_ = idx & 255;
            W2T[idx] = f2b(W2[(size_t)k_ * 16 + n_]);
        }
    }
}

// ---------------------------------------------------------------
// MFMA GEMM: C[M][N] = A(fp32)[M][lda] @ B, with B given transposed bf16
// BT[N-ish][ldb]. BM=64, BN=256, BK=64. 256 thr = 4 waves, wave = 64x64.
// A is reg-staged fp32->bf16 into swizzled LDS; BT via global_load_lds
// with pre-swizzled source. Epilogue: +bias, relu, bf16 store; cols in
// [N, npad) written as 0.
// ---------------------------------------------------------------
template<int BIAS, int RELU>
__global__ __launch_bounds__(256)
void gemm_a32_bt16(const float* __restrict__ A, int lda, int M, int Ka,
                   const u16* __restrict__ BT, int ldb, int N, int npad,
                   const float* __restrict__ bias,
                   u16* __restrict__ C, int ldc, int K)
{
    __shared__ u16 Asm[64 * 64];     // [64 rows][8 slots of 8 bf16], swizzled
    __shared__ u16 Bsm[256 * 64];    // [256 nrows][8 slots], swizzled
    const int t = threadIdx.x;
    const int lane = t & 63;
    const int w = t >> 6;
    const int row0 = blockIdx.x * 64;
    const int n0 = blockIdx.y * 256;

    const f32x4 fz = {0.f, 0.f, 0.f, 0.f};
    f32x4 acc[4][4];
#pragma unroll
    for (int i = 0; i < 4; ++i)
#pragma unroll
        for (int j = 0; j < 4; ++j) acc[i][j] = fz;

    // A staging map: thread -> row t>>2, k-quarter t&3 (16 floats)
    const int ar = t >> 2, akq = t & 3;
    int agr = row0 + ar; if (agr > M - 1) agr = M - 1;
    const float* asrc = A + (size_t)agr * lda + akq * 16;
    const int aslot0 = (akq * 2) ^ (ar & 7);
    const int aslot1 = (akq * 2 + 1) ^ (ar & 7);

    const int l8 = lane >> 3, sl = lane & 7;

    for (int k0 = 0; k0 < K; k0 += 64) {
        // ---- stage BT tile [256][64] via global_load_lds (8 issues) ----
#pragma unroll
        for (int i = 0; i < 8; ++i) {
            int lr = i * 32 + w * 8 + l8;            // 0..255
            int gn = n0 + lr; if (gn > N - 1) gn = N - 1;
            int ss = sl ^ (lr & 7);                   // pre-swizzled source
            const u16* src = BT + (size_t)gn * ldb + k0 + ss * 8;
            __builtin_amdgcn_global_load_lds(AS1(src), AS3(&Bsm[(i * 32 + w * 8) * 64]),
                                             16, 0, 0);
        }
        // ---- stage A tile [64][64]: fp32 load, cvt, swizzled ds_write ----
        bool aval = (k0 + akq * 16) < Ka;
        float4 x0, x1, x2, x3;
        if (aval) {
            x0 = *(const float4*)(asrc + k0);
            x1 = *(const float4*)(asrc + k0 + 4);
            x2 = *(const float4*)(asrc + k0 + 8);
            x3 = *(const float4*)(asrc + k0 + 12);
        } else {
            x0 = x1 = x2 = x3 = make_float4(0.f, 0.f, 0.f, 0.f);
        }
        bf16x8 p0, p1;
        p0[0]=f2b(x0.x); p0[1]=f2b(x0.y); p0[2]=f2b(x0.z); p0[3]=f2b(x0.w);
        p0[4]=f2b(x1.x); p0[5]=f2b(x1.y); p0[6]=f2b(x1.z); p0[7]=f2b(x1.w);
        p1[0]=f2b(x2.x); p1[1]=f2b(x2.y); p1[2]=f2b(x2.z); p1[3]=f2b(x2.w);
        p1[4]=f2b(x3.x); p1[5]=f2b(x3.y); p1[6]=f2b(x3.z); p1[7]=f2b(x3.w);
        *(bf16x8*)&Asm[ar * 64 + aslot0 * 8] = p0;
        *(bf16x8*)&Asm[ar * 64 + aslot1 * 8] = p1;
        __syncthreads();
        // ---- compute: 2 k-chunks of 32 ----
#pragma unroll
        for (int kk = 0; kk < 2; ++kk) {
            bf16x8 afr[4], bfr[4];
#pragma unroll
            for (int mi = 0; mi < 4; ++mi) {
                int r = mi * 16 + (lane & 15);
                int s2 = (kk * 4 + (lane >> 4)) ^ (r & 7);
                afr[mi] = *(const bf16x8*)&Asm[r * 64 + s2 * 8];
            }
#pragma unroll
            for (int ni = 0; ni < 4; ++ni) {
                int nr = w * 64 + ni * 16 + (lane & 15);
                int s2 = (kk * 4 + (lane >> 4)) ^ (nr & 7);
                bfr[ni] = *(const bf16x8*)&Bsm[nr * 64 + s2 * 8];
            }
#pragma unroll
            for (int mi = 0; mi < 4; ++mi)
#pragma unroll
                for (int ni = 0; ni < 4; ++ni)
                    acc[mi][ni] = __builtin_amdgcn_mfma_f32_16x16x32_bf16(
                        afr[mi], bfr[ni], acc[mi][ni], 0, 0, 0);
        }
        __syncthreads();
    }
    // ---- epilogue ----
#pragma unroll
    for (int mi = 0; mi < 4; ++mi) {
        int grb = row0 + mi * 16 + (lane >> 4) * 4;
#pragma unroll
        for (int ni = 0; ni < 4; ++ni) {
            int gc = n0 + w * 64 + ni * 16 + (lane & 15);
            if (gc < npad) {
                float bv = (BIAS && gc < N) ? bias[gc] : 0.f;
#pragma unroll
                for (int rg = 0; rg < 4; ++rg) {
                    int gr = grb + rg;
                    if (gr < M) {
                        float v = acc[mi][ni][rg] + bv;
                        if (RELU) v = fmaxf(v, 0.f);
                        C[(size_t)gr * ldc + gc] = f2b(gc < N ? v : 0.f);
                    }
                }
            }
        }
    }
}

// ---------------------------------------------------------------
// adj16: P[s][i][c] = sum_{j in s-range} A[i][j] * BT[c][j]
// A: bf16 [NN][KP] (AFP32=0) or fp32 [NN][lda] (AFP32=1, on-the-fly cvt)
// BT: bf16 [16][KP] (zero-padded k >= K_valid). No LDS; per-wave MFMA.
// grid (157, 8), 256 thr = 4 waves x 16 rows.
// ---------------------------------------------------------------
template<int AFP32>
__global__ __launch_bounds__(256)
void adj16(const void* __restrict__ Av, long lda,
           const u16* __restrict__ BT,
           float* __restrict__ P, int nch, int nchf, int Kv)
{
    const int t = threadIdx.x, lane = t & 63, w = t >> 6;
    const int s = blockIdx.y;
    int row = blockIdx.x * 64 + w * 16 + (lane & 15);
    if (row > NN - 1) row = NN - 1;
    const int kq = (lane >> 4) * 8;
    const u16* brow = BT + (size_t)(lane & 15) * KP + kq;
    const float* a32 = (const float*)Av + (size_t)row * lda + kq;
    const u16*  a16 = (const u16*) Av + (size_t)row * lda + kq;

    int c0 = (nch * s) >> 3, c1 = (nch * (s + 1)) >> 3;
    int c1f = c1 < nchf ? c1 : nchf;
    f32x4 acc = {0.f, 0.f, 0.f, 0.f};
    int kc = c0;
    for (; kc + 4 <= c1f; kc += 4) {
        bf16x8 a[4], b[4];
#pragma unroll
        for (int u = 0; u < 4; ++u) {
            if (AFP32) {
                float4 x = *(const float4*)(a32 + (size_t)(kc + u) * 32);
                float4 y = *(const float4*)(a32 + (size_t)(kc + u) * 32 + 4);
                bf16x8 r;
                r[0]=f2b(x.x); r[1]=f2b(x.y); r[2]=f2b(x.z); r[3]=f2b(x.w);
                r[4]=f2b(y.x); r[5]=f2b(y.y); r[6]=f2b(y.z); r[7]=f2b(y.w);
                a[u] = r;
            } else {
                a[u] = *(const bf16x8*)(a16 + (size_t)(kc + u) * 32);
            }
            b[u] = *(const bf16x8*)(brow + (size_t)(kc + u) * 32);
        }
#pragma unroll
        for (int u = 0; u < 4; ++u)
            acc = __builtin_amdgcn_mfma_f32_16x16x32_bf16(a[u], b[u], acc, 0, 0, 0);
    }
    for (; kc < c1; ++kc) {
        bf16x8 a = bf16x8{0,0,0,0,0,0,0,0};
        if (kc < nchf || (kc * 32 + kq) < Kv) {
            if (AFP32) {
                float4 x = *(const float4*)(a32 + (size_t)kc * 32);
                float4 y = *(const float4*)(a32 + (size_t)kc * 32 + 4);
                a[0]=f2b(x.x); a[1]=f2b(x.y); a[2]=f2b(x.z); a[3]=f2b(x.w);
                a[4]=f2b(y.x); a[5]=f2b(y.y); a[6]=f2b(y.z); a[7]=f2b(y.w);
            } else {
                a = *(const bf16x8*)(a16 + (size_t)kc * 32);
            }
        }
        bf16x8 b = *(const bf16x8*)(brow + (size_t)kc * 32);
        acc = __builtin_amdgcn_mfma_f32_16x16x32_bf16(a, b, acc, 0, 0, 0);
    }
    int ob = blockIdx.x * 64 + w * 16 + (lane >> 4) * 4;
#pragma unroll
    for (int rg = 0; rg < 4; ++rg) {
        int orow = ob + rg;
        if (orow < NN)
            P[(size_t)s * (NN * 16) + (size_t)orow * 16 + (lane & 15)] = acc[rg];
    }
}

// ---------------------------------------------------------------
// hw2_mfma: outT[16][KP] = (h[NN][256] @ W2)^T via W2T bf16 [16][256]
// grid 157 (157*64 = KP rows exactly); pads written 0
// ---------------------------------------------------------------
__global__ __launch_bounds__(256)
void hw2_mfma(const u16* __restrict__ h, const u16* __restrict__ W2T,
              u16* __restrict__ outT)
{
    const int t = threadIdx.x, lane = t & 63, w = t >> 6;
    int row = blockIdx.x * 64 + w * 16 + (lane & 15);
    int rowc = row < NN ? row : NN - 1;
    const int kq = (lane >> 4) * 8;
    const u16* arow = h + (size_t)rowc * 256 + kq;
    const u16* brow = W2T + (size_t)(lane & 15) * 256 + kq;
    f32x4 acc = {0.f, 0.f, 0.f, 0.f};
#pragma unroll
    for (int kc = 0; kc < 8; ++kc) {
        bf16x8 a = *(const bf16x8*)(arow + kc * 32);
        bf16x8 b = *(const bf16x8*)(brow + kc * 32);
        acc = __builtin_amdgcn_mfma_f32_16x16x32_bf16(a, b, acc, 0, 0, 0);
    }
    int ob = blockIdx.x * 64 + w * 16 + (lane >> 4) * 4;
    int col = lane & 15;
#pragma unroll
    for (int rg = 0; rg < 4; ++rg) {
        int r = ob + rg;
        outT[(size_t)col * KP + r] = f2b(r < NN ? acc[rg] : 0.f);
    }
}

// ---------------------------------------------------------------
// softmax_e: logits = sum_s P[s] + b2; E = B0 = softmax(logits) - 1/16
// ---------------------------------------------------------------
__global__ __launch_bounds__(256)
void softmax_e(const float* __restrict__ P, const float* __restrict__ b2,
               float* __restrict__ E, float* __restrict__ Bout)
{
    int i = blockIdx.x * 256 + threadIdx.x;
    if (i >= NN) return;
    float l[16];
#pragma unroll
    for (int k = 0; k < 16; ++k) l[k] = b2[k];
#pragma unroll
    for (int s = 0; s < 8; ++s) {
        const float4* p4 = (const float4*)(P + (size_t)s * (NN * 16) + (size_t)i * 16);
        float4 a = p4[0], b = p4[1], c = p4[2], d = p4[3];
        l[0]+=a.x;  l[1]+=a.y;  l[2]+=a.z;  l[3]+=a.w;
        l[4]+=b.x;  l[5]+=b.y;  l[6]+=b.z;  l[7]+=b.w;
        l[8]+=c.x;  l[9]+=c.y;  l[10]+=c.z; l[11]+=c.w;
        l[12]+=d.x; l[13]+=d.y; l[14]+=d.z; l[15]+=d.w;
    }
    float mx = l[0];
#pragma unroll
    for (int k = 1; k < 16; ++k) mx = fmaxf(mx, l[k]);
    float ssum = 0.f;
#pragma unroll
    for (int k = 0; k < 16; ++k) { l[k] = __expf(l[k] - mx); ssum += l[k]; }
    float inv = 1.f / ssum;
#pragma unroll
    for (int k = 0; k < 16; ++k) {
        float e = l[k] * inv - INV_C;
        E[(size_t)i * 16 + k] = e;
        Bout[(size_t)i * 16 + k] = e;
    }
}

// ---------------------------------------------------------------
// bmm_h: outT[16][KP] = (Bin[NN][16] @ H[16][16])^T bf16, pads 0
// ---------------------------------------------------------------
__global__ __launch_bounds__(256)
void bmm_h(const float* __restrict__ Bin, const float* __restrict__ H,
           u16* __restrict__ outT)
{
    __shared__ float Hs[256];
    int t = threadIdx.x;
    Hs[t] = H[t];
    __syncthreads();
    int r = blockIdx.x * 256 + t;
    if (r >= KP) return;
    float acc[16];
#pragma unroll
    for (int k = 0; k < 16; ++k) acc[k] = 0.f;
    if (r < NN) {
        const float4* b4 = (const float4*)(Bin + (size_t)r * 16);
        float4 xv[4] = {b4[0], b4[1], b4[2], b4[3]};
#pragma unroll
        for (int m = 0; m < 16; ++m) {
            float x = ((const float*)xv)[m];
            const float4* h4 = (const float4*)&Hs[m * 16];
#pragma unroll
            for (int k4 = 0; k4 < 4; ++k4) {
                float4 hh = h4[k4];
                acc[k4*4+0] += x * hh.x; acc[k4*4+1] += x * hh.y;
                acc[k4*4+2] += x * hh.z; acc[k4*4+3] += x * hh.w;
            }
        }
    }
#pragma unroll
    for (int k = 0; k < 16; ++k)
        outT[(size_t)k * KP + r] = f2b(acc[k]);
}

// ---------------------------------------------------------------
// combine: out = E + sum_s P[s] + addc   (float4 granularity)
// ---------------------------------------------------------------
__global__ __launch_bounds__(256)
void combine_k(const float* __restrict__ E, const float* __restrict__ P,
               float* __restrict__ out, float addc)
{
    int i4 = blockIdx.x * 256 + threadIdx.x;
    if (i4 >= NN * 4) return;
    float4 v = ((const float4*)E)[i4];
#pragma unroll
    for (int s = 0; s < 8; ++s) {
        float4 p = ((const float4*)(P + (size_t)s * (NN * 16)))[i4];
        v.x += p.x; v.y += p.y; v.z += p.z; v.w += p.w;
    }
    v.x += addc; v.y += addc; v.z += addc; v.w += addc;
    ((float4*)out)[i4] = v;
}

extern "C" void kernel_launch(void* const* d_in, const int* in_sizes, int n_in,
                              void* d_out, int out_size, void* d_ws, size_t ws_size,
                              hipStream_t stream)
{
    const float* raw_adj    = (const float*)d_in[0];
    const float* normed_adj = (const float*)d_in[1];
    const float* features   = (const float*)d_in[2];
    const float* W1 = (const float*)d_in[5];
    const float* b1 = (const float*)d_in[6];
    const float* W2 = (const float*)d_in[7];
    const float* b2 = (const float*)d_in[8];
    const float* H  = (const float*)d_in[9];
    float* out = (float*)d_out;

    char* ws = (char*)d_ws;
    // P/E/B alias feat_bf (feat_bf dead before P first written)
    float* P      = (float*)(ws + 0);                 //  5,120,000
    float* E      = (float*)(ws + 5120000);           //    640,000
    float* Bbuf   = (float*)(ws + 5760000);           //    640,000
    u16*   featbf = (u16*)  (ws + 0);                 // 10,240,000 (alias)
    float* W1T    = (float*)(ws + 10240000);          //    524,288
    u16*   W2T    = (u16*)  (ws + 10764288);          //      8,192
    u16*   XWT    = (u16*)  (ws + 10772480);          //  5,144,576
    u16*   hbf    = (u16*)  (ws + 15917056);          //  5,120,000
    u16*   hw2T   = (u16*)  (ws + 21037056);          //    321,536
    u16*   bhT    = (u16*)  (ws + 21358592);          //    321,536
    u16*   ArBf   = (u16*)  (ws + 21680128);          // 200,960,000
    const bool rawbf = ws_size >= (size_t)222640128;

    // 1) conversions / transposes
    cvt_feat<<<2500, 256, 0, stream>>>(features, featbf);
    w12t<<<528, 256, 0, stream>>>(W1, W2, W1T, W2T);
    if (rawbf)
        cvt_pad<<<dim3(5, NN), 256, 0, stream>>>(raw_adj, ArBf);

    // 2) XWT[256][KP] = (features @ W1)^T  ==  W1T[256,512] @ features^T
    gemm_a32_bt16<0, 0><<<dim3(4, 40), 256, 0, stream>>>(
        W1T, 512, 256, 512, featbf, 512, NN, KP, nullptr, XWT, KP, 512);

    // 3) h = relu(normed_adj @ XW + b1) -> bf16 [NN][256]
    gemm_a32_bt16<1, 1><<<dim3(157, 1), 256, 0, stream>>>(
        normed_adj, NN, NN, NN, XWT, KP, 256, 256, b1, hbf, 256, KP);

    // 4) hw2T = (h @ W2)^T bf16 [16][KP]
    hw2_mfma<<<157, 256, 0, stream>>>(hbf, W2T, hw2T);

    // 5) logits partials = normed_adj @ hw2  (fp32 A on the fly)
    adj16<1><<<dim3(157, 8), 256, 0, stream>>>(
        (const void*)normed_adj, NN, hw2T, P, 313, 312, NN);

    // 6) softmax -> E, B0
    softmax_e<<<40, 256, 0, stream>>>(P, b2, E, Bbuf);

    // 7) 4 belief-propagation iterations
    for (int it = 0; it < 4; ++it) {
        bmm_h<<<40, 256, 0, stream>>>(Bbuf, H, bhT);
        if (rawbf)
            adj16<0><<<dim3(157, 8), 256, 0, stream>>>(
                (const void*)ArBf, KP, bhT, P, 314, 314, KP);
        else
            adj16<1><<<dim3(157, 8), 256, 0, stream>>>(
                (const void*)raw_adj, NN, bhT, P, 313, 312, NN);
        const bool last = (it == 3);
        combine_k<<<157, 256, 0, stream>>>(E, P, last ? out : Bbuf,
                                           last ? INV_C : 0.f);
    }
}

// Round 3
// 609.123 us; speedup vs baseline: 8.1221x; 1.1818x over previous
//
#include <hip/hip_runtime.h>

#define NN 10000
#define KP 10048           // NN padded to multiple of 64
static constexpr float INV_C = 1.0f / 16.0f;

typedef __attribute__((ext_vector_type(8))) short bf16x8;
typedef __attribute__((ext_vector_type(4))) float f32x4;
typedef unsigned short u16;
typedef unsigned int u32;

__device__ __forceinline__ u16 f2b(float f) {            // RNE f32 -> bf16
    union { float f; u32 u; } v; v.f = f;
    u32 r = v.u + 0x7FFFu + ((v.u >> 16) & 1u);
    return (u16)(r >> 16);
}

#define AS1(p) ((__attribute__((address_space(1))) void*)(p))
#define AS3(p) ((__attribute__((address_space(3))) void*)(p))

// ---------------------------------------------------------------
// cvt_feat: fp32 [NN][512] -> bf16 [NN][512]; grid 2500 exact
// ---------------------------------------------------------------
__global__ __launch_bounds__(256)
void cvt_feat(const float* __restrict__ src, u16* __restrict__ dst)
{
    int c = blockIdx.x * 256 + threadIdx.x;    // 640000 chunks of 8
    size_t base = (size_t)c * 8;
    const float4* s4 = (const float4*)(src + base);
    float4 a = s4[0], b = s4[1];
    bf16x8 o;
    o[0]=f2b(a.x); o[1]=f2b(a.y); o[2]=f2b(a.z); o[3]=f2b(a.w);
    o[4]=f2b(b.x); o[5]=f2b(b.y); o[6]=f2b(b.z); o[7]=f2b(b.w);
    *(bf16x8*)(dst + base) = o;
}

// ---------------------------------------------------------------
// w12t: W1T fp32 [256][512] <- W1 [512][256];  W2T bf16 [16][256] <- W2 [256][16]
// ---------------------------------------------------------------
__global__ __launch_bounds__(256)
void w12t(const float* __restrict__ W1, const float* __restrict__ W2,
          float* __restrict__ W1T, u16* __restrict__ W2T)
{
    int bid = blockIdx.x, t = threadIdx.x;
    if (bid < 512) {
        int idx = bid * 256 + t;           // n*512 + k
        int n = idx >> 9, k = idx & 511;
        W1T[idx] = W1[(size_t)k * 256 + n];
    } else {
        int idx = (bid - 512) * 256 + t;   // 4096 elems: n_*256 + k_
        if (idx < 4096) {
            int n_ = idx >> 8, k_ = idx & 255;
            W2T[idx] = f2b(W2[(size_t)k_ * 16 + n_]);
        }
    }
}

// ---------------------------------------------------------------
// Generic MFMA GEMM (used for XWT; also ultra-low fallback):
// C[M][N] = A(fp32)[M][lda] @ B, B transposed bf16 BT[N][ldb].
// BM=64, BN=256, BK=64; 256 thr = 4 waves.
// ---------------------------------------------------------------
template<int BIAS, int RELU>
__global__ __launch_bounds__(256)
void gemm_a32_bt16(const float* __restrict__ A, int lda, int M, int Ka,
                   const u16* __restrict__ BT, int ldb, int N, int npad,
                   const float* __restrict__ bias,
                   u16* __restrict__ C, int ldc, int K)
{
    __shared__ u16 Asm[64 * 64];
    __shared__ u16 Bsm[256 * 64];
    const int t = threadIdx.x;
    const int lane = t & 63;
    const int w = t >> 6;
    const int row0 = blockIdx.x * 64;
    const int n0 = blockIdx.y * 256;

    const f32x4 fz = {0.f, 0.f, 0.f, 0.f};
    f32x4 acc[4][4];
#pragma unroll
    for (int i = 0; i < 4; ++i)
#pragma unroll
        for (int j = 0; j < 4; ++j) acc[i][j] = fz;

    const int ar = t >> 2, akq = t & 3;
    int agr = row0 + ar; if (agr > M - 1) agr = M - 1;
    const float* asrc = A + (size_t)agr * lda + akq * 16;
    const int aslot0 = (akq * 2) ^ (ar & 7);
    const int aslot1 = (akq * 2 + 1) ^ (ar & 7);
    const int l8 = lane >> 3, sl = lane & 7;

    for (int k0 = 0; k0 < K; k0 += 64) {
#pragma unroll
        for (int i = 0; i < 8; ++i) {
            int lr = i * 32 + w * 8 + l8;
            int gn = n0 + lr; if (gn > N - 1) gn = N - 1;
            int ss = sl ^ (lr & 7);
            const u16* src = BT + (size_t)gn * ldb + k0 + ss * 8;
            __builtin_amdgcn_global_load_lds(AS1(src), AS3(&Bsm[(i * 32 + w * 8) * 64]),
                                             16, 0, 0);
        }
        bool aval = (k0 + akq * 16) < Ka;
        float4 x0, x1, x2, x3;
        if (aval) {
            x0 = *(const float4*)(asrc + k0);
            x1 = *(const float4*)(asrc + k0 + 4);
            x2 = *(const float4*)(asrc + k0 + 8);
            x3 = *(const float4*)(asrc + k0 + 12);
        } else {
            x0 = x1 = x2 = x3 = make_float4(0.f, 0.f, 0.f, 0.f);
        }
        bf16x8 p0, p1;
        p0[0]=f2b(x0.x); p0[1]=f2b(x0.y); p0[2]=f2b(x0.z); p0[3]=f2b(x0.w);
        p0[4]=f2b(x1.x); p0[5]=f2b(x1.y); p0[6]=f2b(x1.z); p0[7]=f2b(x1.w);
        p1[0]=f2b(x2.x); p1[1]=f2b(x2.y); p1[2]=f2b(x2.z); p1[3]=f2b(x2.w);
        p1[4]=f2b(x3.x); p1[5]=f2b(x3.y); p1[6]=f2b(x3.z); p1[7]=f2b(x3.w);
        *(bf16x8*)&Asm[ar * 64 + aslot0 * 8] = p0;
        *(bf16x8*)&Asm[ar * 64 + aslot1 * 8] = p1;
        __syncthreads();
#pragma unroll
        for (int kk = 0; kk < 2; ++kk) {
            bf16x8 afr[4], bfr[4];
#pragma unroll
            for (int mi = 0; mi < 4; ++mi) {
                int r = mi * 16 + (lane & 15);
                int s2 = (kk * 4 + (lane >> 4)) ^ (r & 7);
                afr[mi] = *(const bf16x8*)&Asm[r * 64 + s2 * 8];
            }
#pragma unroll
            for (int ni = 0; ni < 4; ++ni) {
                int nr = w * 64 + ni * 16 + (lane & 15);
                int s2 = (kk * 4 + (lane >> 4)) ^ (nr & 7);
                bfr[ni] = *(const bf16x8*)&Bsm[nr * 64 + s2 * 8];
            }
#pragma unroll
            for (int mi = 0; mi < 4; ++mi)
#pragma unroll
                for (int ni = 0; ni < 4; ++ni)
                    acc[mi][ni] = __builtin_amdgcn_mfma_f32_16x16x32_bf16(
                        afr[mi], bfr[ni], acc[mi][ni], 0, 0, 0);
        }
        __syncthreads();
    }
#pragma unroll
    for (int mi = 0; mi < 4; ++mi) {
        int grb = row0 + mi * 16 + (lane >> 4) * 4;
#pragma unroll
        for (int ni = 0; ni < 4; ++ni) {
            int gc = n0 + w * 64 + ni * 16 + (lane & 15);
            if (gc < npad) {
                float bv = (BIAS && gc < N) ? bias[gc] : 0.f;
#pragma unroll
                for (int rg = 0; rg < 4; ++rg) {
                    int gr = grb + rg;
                    if (gr < M) {
                        float v = acc[mi][ni][rg] + bv;
                        if (RELU) v = fmaxf(v, 0.f);
                        C[(size_t)gr * ldc + gc] = f2b(gc < N ? v : 0.f);
                    }
                }
            }
        }
    }
}

// ---------------------------------------------------------------
// gemm_na: split-K pass over normed_adj.
// Pws[s][NN][256] += A[64rows][kchunk(s)] @ XWT^T ; optional bf16 A copy.
// grid (157, 8). BT = XWT [256][KP] bf16.
// ---------------------------------------------------------------
template<int CVT>
__global__ __launch_bounds__(256)
void gemm_na(const float* __restrict__ A, const u16* __restrict__ BT,
             float* __restrict__ Pws, u16* __restrict__ Acvt)
{
    __shared__ u16 Asm[64 * 64];
    __shared__ u16 Bsm[256 * 64];
    const int t = threadIdx.x;
    const int lane = t & 63;
    const int w = t >> 6;
    const int row0 = blockIdx.x * 64;
    const int s = blockIdx.y;
    const int c0 = (157 * s) >> 3, c1 = (157 * (s + 1)) >> 3;

    const f32x4 fz = {0.f, 0.f, 0.f, 0.f};
    f32x4 acc[4][4];
#pragma unroll
    for (int i = 0; i < 4; ++i)
#pragma unroll
        for (int j = 0; j < 4; ++j) acc[i][j] = fz;

    const int ar = t >> 2, akq = t & 3;
    const int grow = row0 + ar;
    const int agr = grow < NN ? grow : NN - 1;
    const float* asrc = A + (size_t)agr * NN + akq * 16;
    const int aslot0 = (akq * 2) ^ (ar & 7);
    const int aslot1 = (akq * 2 + 1) ^ (ar & 7);
    const int l8 = lane >> 3, sl = lane & 7;

    for (int ck = c0; ck < c1; ++ck) {
        const int k0 = ck * 64;
#pragma unroll
        for (int i = 0; i < 8; ++i) {
            int lr = i * 32 + w * 8 + l8;            // 0..255, N=256 exact
            int ss = sl ^ (lr & 7);
            const u16* src = BT + (size_t)lr * KP + k0 + ss * 8;
            __builtin_amdgcn_global_load_lds(AS1(src), AS3(&Bsm[(i * 32 + w * 8) * 64]),
                                             16, 0, 0);
        }
        const int kq0 = k0 + akq * 16;
        bool aval = kq0 < NN;                         // NN multiple of 16
        float4 x0, x1, x2, x3;
        if (aval) {
            x0 = *(const float4*)(asrc + k0);
            x1 = *(const float4*)(asrc + k0 + 4);
            x2 = *(const float4*)(asrc + k0 + 8);
            x3 = *(const float4*)(asrc + k0 + 12);
        } else {
            x0 = x1 = x2 = x3 = make_float4(0.f, 0.f, 0.f, 0.f);
        }
        bf16x8 p0, p1;
        p0[0]=f2b(x0.x); p0[1]=f2b(x0.y); p0[2]=f2b(x0.z); p0[3]=f2b(x0.w);
        p0[4]=f2b(x1.x); p0[5]=f2b(x1.y); p0[6]=f2b(x1.z); p0[7]=f2b(x1.w);
        p1[0]=f2b(x2.x); p1[1]=f2b(x2.y); p1[2]=f2b(x2.z); p1[3]=f2b(x2.w);
        p1[4]=f2b(x3.x); p1[5]=f2b(x3.y); p1[6]=f2b(x3.z); p1[7]=f2b(x3.w);
        *(bf16x8*)&Asm[ar * 64 + aslot0 * 8] = p0;
        *(bf16x8*)&Asm[ar * 64 + aslot1 * 8] = p1;
        if (CVT && grow < NN) {
            *(bf16x8*)(Acvt + (size_t)grow * KP + kq0) = p0;
            *(bf16x8*)(Acvt + (size_t)grow * KP + kq0 + 8) = p1;
        }
        __syncthreads();
#pragma unroll
        for (int kk = 0; kk < 2; ++kk) {
            bf16x8 afr[4], bfr[4];
#pragma unroll
            for (int mi = 0; mi < 4; ++mi) {
                int r = mi * 16 + (lane & 15);
                int s2 = (kk * 4 + (lane >> 4)) ^ (r & 7);
                afr[mi] = *(const bf16x8*)&Asm[r * 64 + s2 * 8];
            }
#pragma unroll
            for (int ni = 0; ni < 4; ++ni) {
                int nr = w * 64 + ni * 16 + (lane & 15);
                int s2 = (kk * 4 + (lane >> 4)) ^ (nr & 7);
                bfr[ni] = *(const bf16x8*)&Bsm[nr * 64 + s2 * 8];
            }
#pragma unroll
            for (int mi = 0; mi < 4; ++mi)
#pragma unroll
                for (int ni = 0; ni < 4; ++ni)
                    acc[mi][ni] = __builtin_amdgcn_mfma_f32_16x16x32_bf16(
                        afr[mi], bfr[ni], acc[mi][ni], 0, 0, 0);
        }
        __syncthreads();
    }
    float* outp = Pws + (size_t)s * NN * 256;
#pragma unroll
    for (int mi = 0; mi < 4; ++mi) {
        int grb = row0 + mi * 16 + (lane >> 4) * 4;
#pragma unroll
        for (int ni = 0; ni < 4; ++ni) {
            int gc = w * 64 + ni * 16 + (lane & 15);
#pragma unroll
            for (int rg = 0; rg < 4; ++rg) {
                int gr = grb + rg;
                if (gr < NN)
                    outp[(size_t)gr * 256 + gc] = acc[mi][ni][rg];
            }
        }
    }
}

// ---------------------------------------------------------------
// reduce_h: hbf = relu(sum_s Pws[s] + b1) -> bf16 [NN][256]; grid 1250
// ---------------------------------------------------------------
__global__ __launch_bounds__(256)
void reduce_h(const float* __restrict__ Pws, const float* __restrict__ b1,
              u16* __restrict__ hbf)
{
    int i8 = blockIdx.x * 256 + threadIdx.x;
    if (i8 >= NN * 256 / 8) return;
    size_t base = (size_t)i8 * 8;
    int col = (int)(base & 255);
    float v[8];
#pragma unroll
    for (int j = 0; j < 8; ++j) v[j] = b1[col + j];
#pragma unroll
    for (int s = 0; s < 8; ++s) {
        const float4* p = (const float4*)(Pws + (size_t)s * NN * 256 + base);
        float4 a = p[0], b = p[1];
        v[0]+=a.x; v[1]+=a.y; v[2]+=a.z; v[3]+=a.w;
        v[4]+=b.x; v[5]+=b.y; v[6]+=b.z; v[7]+=b.w;
    }
    bf16x8 o;
#pragma unroll
    for (int j = 0; j < 8; ++j) o[j] = f2b(fmaxf(v[j], 0.f));
    *(bf16x8*)(hbf + base) = o;
}

// ---------------------------------------------------------------
// adj16: Pout[s][i][c] = sum_{j in s-range} A[i][j] * BT[c][j]
// AFP32: A fp32 (on-the-fly cvt) else bf16 [*,KP]. CVT: write bf16 copy.
// grid (157, 8), 4 waves x 16 rows.
// ---------------------------------------------------------------
template<int AFP32, int CVT>
__global__ __launch_bounds__(256)
void adj16(const void* __restrict__ Av, long lda,
           const u16* __restrict__ BT,
           float* __restrict__ Pout, int nch, int nchf,
           u16* __restrict__ Acvt)
{
    const int t = threadIdx.x, lane = t & 63, w = t >> 6;
    const int s = blockIdx.y;
    const int rowu = blockIdx.x * 64 + w * 16 + (lane & 15);
    const int row = rowu < NN ? rowu : NN - 1;
    const int kq = (lane >> 4) * 8;
    const u16* brow = BT + (size_t)(lane & 15) * KP + kq;
    const float* a32 = (const float*)Av + (size_t)row * lda + kq;
    const u16*  a16 = (const u16*) Av + (size_t)row * lda + kq;
    u16* cvtp = CVT ? (Acvt + (size_t)rowu * KP + kq) : (u16*)0;
    const bool wok = CVT && (rowu < NN);

    int c0 = (nch * s) >> 3, c1 = (nch * (s + 1)) >> 3;
    int c1f = c1 < nchf ? c1 : nchf;
    f32x4 acc = {0.f, 0.f, 0.f, 0.f};
    int kc = c0;
    for (; kc + 4 <= c1f; kc += 4) {
        bf16x8 a[4], b[4];
#pragma unroll
        for (int u = 0; u < 4; ++u) {
            if (AFP32) {
                float4 x = *(const float4*)(a32 + (size_t)(kc + u) * 32);
                float4 y = *(const float4*)(a32 + (size_t)(kc + u) * 32 + 4);
                bf16x8 r;
                r[0]=f2b(x.x); r[1]=f2b(x.y); r[2]=f2b(x.z); r[3]=f2b(x.w);
                r[4]=f2b(y.x); r[5]=f2b(y.y); r[6]=f2b(y.z); r[7]=f2b(y.w);
                a[u] = r;
            } else {
                a[u] = *(const bf16x8*)(a16 + (size_t)(kc + u) * 32);
            }
            b[u] = *(const bf16x8*)(brow + (size_t)(kc + u) * 32);
        }
        if (CVT && wok) {
#pragma unroll
            for (int u = 0; u < 4; ++u)
                *(bf16x8*)(cvtp + (size_t)(kc + u) * 32) = a[u];
        }
#pragma unroll
        for (int u = 0; u < 4; ++u)
            acc = __builtin_amdgcn_mfma_f32_16x16x32_bf16(a[u], b[u], acc, 0, 0, 0);
    }
    for (; kc < c1; ++kc) {
        bf16x8 a = bf16x8{0,0,0,0,0,0,0,0};
        if (AFP32) {
            if (kc * 32 + kq < NN) {          // 8-float group fully valid
                float4 x = *(const float4*)(a32 + (size_t)kc * 32);
                float4 y = *(const float4*)(a32 + (size_t)kc * 32 + 4);
                a[0]=f2b(x.x); a[1]=f2b(x.y); a[2]=f2b(x.z); a[3]=f2b(x.w);
                a[4]=f2b(y.x); a[5]=f2b(y.y); a[6]=f2b(y.z); a[7]=f2b(y.w);
            }
        } else {
            a = *(const bf16x8*)(a16 + (size_t)kc * 32);
        }
        if (CVT && wok)
            *(bf16x8*)(cvtp + (size_t)kc * 32) = a;
        bf16x8 b = *(const bf16x8*)(brow + (size_t)kc * 32);
        acc = __builtin_amdgcn_mfma_f32_16x16x32_bf16(a, b, acc, 0, 0, 0);
    }
    int ob = blockIdx.x * 64 + w * 16 + (lane >> 4) * 4;
#pragma unroll
    for (int rg = 0; rg < 4; ++rg) {
        int orow = ob + rg;
        if (orow < NN)
            Pout[(size_t)s * (NN * 16) + (size_t)orow * 16 + (lane & 15)] = acc[rg];
    }
}

// ---------------------------------------------------------------
// hw2_mfma: outT[16][KP] = (h[NN][256] @ W2)^T via W2T bf16 [16][256]
// ---------------------------------------------------------------
__global__ __launch_bounds__(256)
void hw2_mfma(const u16* __restrict__ h, const u16* __restrict__ W2T,
              u16* __restrict__ outT)
{
    const int t = threadIdx.x, lane = t & 63, w = t >> 6;
    int row = blockIdx.x * 64 + w * 16 + (lane & 15);
    int rowc = row < NN ? row : NN - 1;
    const int kq = (lane >> 4) * 8;
    const u16* arow = h + (size_t)rowc * 256 + kq;
    const u16* brow = W2T + (size_t)(lane & 15) * 256 + kq;
    f32x4 acc = {0.f, 0.f, 0.f, 0.f};
#pragma unroll
    for (int kc = 0; kc < 8; ++kc) {
        bf16x8 a = *(const bf16x8*)(arow + kc * 32);
        bf16x8 b = *(const bf16x8*)(brow + kc * 32);
        acc = __builtin_amdgcn_mfma_f32_16x16x32_bf16(a, b, acc, 0, 0, 0);
    }
    int ob = blockIdx.x * 64 + w * 16 + (lane >> 4) * 4;
    int col = lane & 15;
#pragma unroll
    for (int rg = 0; rg < 4; ++rg) {
        int r = ob + rg;
        outT[(size_t)col * KP + r] = f2b(r < NN ? acc[rg] : 0.f);
    }
}

// ---------------------------------------------------------------
// softmax_e_h: logits = sum_s P[s] + b2; E = softmax - 1/16;
// bhT = (E @ H)^T bf16 [16][KP] (pads 0). grid 40.
// ---------------------------------------------------------------
__global__ __launch_bounds__(256)
void softmax_e_h(const float* __restrict__ P, const float* __restrict__ b2,
                 const float* __restrict__ H, float* __restrict__ E,
                 u16* __restrict__ bhT)
{
    __shared__ float Hs[256];
    const int t = threadIdx.x;
    Hs[t] = H[t];
    __syncthreads();
    int r = blockIdx.x * 256 + t;
    if (r >= KP) return;
    float l[16];
    if (r < NN) {
#pragma unroll
        for (int k = 0; k < 16; ++k) l[k] = b2[k];
#pragma unroll
        for (int s = 0; s < 8; ++s) {
            const float4* p4 = (const float4*)(P + (size_t)s * (NN * 16) + (size_t)r * 16);
            float4 a = p4[0], b = p4[1], c = p4[2], d = p4[3];
            l[0]+=a.x;  l[1]+=a.y;  l[2]+=a.z;  l[3]+=a.w;
            l[4]+=b.x;  l[5]+=b.y;  l[6]+=b.z;  l[7]+=b.w;
            l[8]+=c.x;  l[9]+=c.y;  l[10]+=c.z; l[11]+=c.w;
            l[12]+=d.x; l[13]+=d.y; l[14]+=d.z; l[15]+=d.w;
        }
        float mx = l[0];
#pragma unroll
        for (int k = 1; k < 16; ++k) mx = fmaxf(mx, l[k]);
        float ssum = 0.f;
#pragma unroll
        for (int k = 0; k < 16; ++k) { l[k] = __expf(l[k] - mx); ssum += l[k]; }
        float inv = 1.f / ssum;
#pragma unroll
        for (int k = 0; k < 16; ++k) {
            l[k] = l[k] * inv - INV_C;
            E[(size_t)r * 16 + k] = l[k];
        }
    } else {
#pragma unroll
        for (int k = 0; k < 16; ++k) l[k] = 0.f;
    }
    float acc[16];
#pragma unroll
    for (int k = 0; k < 16; ++k) acc[k] = 0.f;
#pragma unroll
    for (int m = 0; m < 16; ++m) {
        float x = l[m];
        const float4* h4 = (const float4*)&Hs[m * 16];
#pragma unroll
        for (int k4 = 0; k4 < 4; ++k4) {
            float4 hh = h4[k4];
            acc[k4*4+0] += x * hh.x; acc[k4*4+1] += x * hh.y;
            acc[k4*4+2] += x * hh.z; acc[k4*4+3] += x * hh.w;
        }
    }
#pragma unroll
    for (int k = 0; k < 16; ++k)
        bhT[(size_t)k * KP + r] = f2b(acc[k]);
}

// ---------------------------------------------------------------
// combine_bmm: B = E + sum_s P[s];
// LAST: out = B + 1/16 (fp32). else: bhT = (B @ H)^T bf16. grid 40.
// ---------------------------------------------------------------
template<int LAST>
__global__ __launch_bounds__(256)
void combine_bmm(const float* __restrict__ E, const float* __restrict__ P,
                 const float* __restrict__ H, u16* __restrict__ bhT,
                 float* __restrict__ out)
{
    __shared__ float Hs[256];
    const int t = threadIdx.x;
    Hs[t] = H[t];
    __syncthreads();
    int r = blockIdx.x * 256 + t;
    if (r >= KP) return;
    float Bv[16];
    if (r < NN) {
        const float4* e4 = (const float4*)(E + (size_t)r * 16);
        float4 a = e4[0], b = e4[1], c = e4[2], d = e4[3];
        Bv[0]=a.x;  Bv[1]=a.y;  Bv[2]=a.z;  Bv[3]=a.w;
        Bv[4]=b.x;  Bv[5]=b.y;  Bv[6]=b.z;  Bv[7]=b.w;
        Bv[8]=c.x;  Bv[9]=c.y;  Bv[10]=c.z; Bv[11]=c.w;
        Bv[12]=d.x; Bv[13]=d.y; Bv[14]=d.z; Bv[15]=d.w;
#pragma unroll
        for (int s = 0; s < 8; ++s) {
            const float4* p4 = (const float4*)(P + (size_t)s * (NN * 16) + (size_t)r * 16);
            float4 pa = p4[0], pb = p4[1], pc = p4[2], pd = p4[3];
            Bv[0]+=pa.x;  Bv[1]+=pa.y;  Bv[2]+=pa.z;  Bv[3]+=pa.w;
            Bv[4]+=pb.x;  Bv[5]+=pb.y;  Bv[6]+=pb.z;  Bv[7]+=pb.w;
            Bv[8]+=pc.x;  Bv[9]+=pc.y;  Bv[10]+=pc.z; Bv[11]+=pc.w;
            Bv[12]+=pd.x; Bv[13]+=pd.y; Bv[14]+=pd.z; Bv[15]+=pd.w;
        }
    } else {
#pragma unroll
        for (int k = 0; k < 16; ++k) Bv[k] = 0.f;
    }
    if (LAST) {
        if (r < NN) {
            float4 o[4];
#pragma unroll
            for (int q = 0; q < 4; ++q) {
                o[q].x = Bv[q*4+0] + INV_C; o[q].y = Bv[q*4+1] + INV_C;
                o[q].z = Bv[q*4+2] + INV_C; o[q].w = Bv[q*4+3] + INV_C;
                ((float4*)(out + (size_t)r * 16))[q] = o[q];
            }
        }
    } else {
        float acc[16];
#pragma unroll
        for (int k = 0; k < 16; ++k) acc[k] = 0.f;
#pragma unroll
        for (int m = 0; m < 16; ++m) {
            float x = Bv[m];
            const float4* h4 = (const float4*)&Hs[m * 16];
#pragma unroll
            for (int k4 = 0; k4 < 4; ++k4) {
                float4 hh = h4[k4];
                acc[k4*4+0] += x * hh.x; acc[k4*4+1] += x * hh.y;
                acc[k4*4+2] += x * hh.z; acc[k4*4+3] += x * hh.w;
            }
        }
#pragma unroll
        for (int k = 0; k < 16; ++k)
            bhT[(size_t)k * KP + r] = f2b(acc[k]);
    }
}

extern "C" void kernel_launch(void* const* d_in, const int* in_sizes, int n_in,
                              void* d_out, int out_size, void* d_ws, size_t ws_size,
                              hipStream_t stream)
{
    const float* raw_adj    = (const float*)d_in[0];
    const float* normed_adj = (const float*)d_in[1];
    const float* features   = (const float*)d_in[2];
    const float* W1 = (const float*)d_in[5];
    const float* b1 = (const float*)d_in[6];
    const float* W2 = (const float*)d_in[7];
    const float* b2 = (const float*)d_in[8];
    const float* H  = (const float*)d_in[9];
    float* out = (float*)d_out;

    char* ws = (char*)d_ws;
    // fixed small region (featbf aliased later by P/E/Bbuf)
    u16*   featbf = (u16*)  (ws + 0);                 // 10,240,000
    float* P      = (float*)(ws + 0);                 //  5,120,000 (alias)
    float* E      = (float*)(ws + 5120000);           //    640,000 (alias)
    float* W1T    = (float*)(ws + 10240000);          //    524,288
    u16*   W2T    = (u16*)  (ws + 10764288);          //      8,192
    u16*   XWT    = (u16*)  (ws + 10772480);          //  5,144,576
    u16*   hbf    = (u16*)  (ws + 15917056);          //  5,120,000
    u16*   hw2T   = (u16*)  (ws + 21037056);          //    321,536
    u16*   bhT    = (u16*)  (ws + 21358592);          //    321,536
    // big region @ 21,680,128
    const bool full  = ws_size >= (size_t)304560128;  // An_bf + Pws (ArBf aliases)
    const bool mid   = ws_size >= (size_t)222640128;  // shared {Pws, then ArBf}
    const bool low   = ws_size >= (size_t)103600128;  // Pws only
    u16*   An_bf = (u16*)  (ws + 21680128);                       // 200,960,000
    float* Pws   = (float*)(ws + (full ? 222640128 : 21680128));  //  81,920,000
    u16*   ArBf  = (u16*)  (ws + 21680128);                       // 200,960,000

    // 1) conversions / transposes
    cvt_feat<<<2500, 256, 0, stream>>>(features, featbf);
    w12t<<<528, 256, 0, stream>>>(W1, W2, W1T, W2T);

    // 2) XWT[256][KP] = (features @ W1)^T
    gemm_a32_bt16<0, 0><<<dim3(4, 40), 256, 0, stream>>>(
        W1T, 512, 256, 512, featbf, 512, NN, KP, nullptr, XWT, KP, 512);

    // 3) h = relu(normed_adj @ XW + b1)
    if (low) {
        if (full)
            gemm_na<1><<<dim3(157, 8), 256, 0, stream>>>(normed_adj, XWT, Pws, An_bf);
        else
            gemm_na<0><<<dim3(157, 8), 256, 0, stream>>>(normed_adj, XWT, Pws, nullptr);
        reduce_h<<<1250, 256, 0, stream>>>(Pws, b1, hbf);
    } else {
        gemm_a32_bt16<1, 1><<<dim3(157, 1), 256, 0, stream>>>(
            normed_adj, NN, NN, NN, XWT, KP, 256, 256, b1, hbf, 256, KP);
    }

    // 4) hw2T = (h @ W2)^T
    hw2_mfma<<<157, 256, 0, stream>>>(hbf, W2T, hw2T);

    // 5) logits partials = normed_adj @ hw2
    if (full)
        adj16<0, 0><<<dim3(157, 8), 256, 0, stream>>>(
            (const void*)An_bf, KP, hw2T, P, 314, 314, nullptr);
    else
        adj16<1, 0><<<dim3(157, 8), 256, 0, stream>>>(
            (const void*)normed_adj, NN, hw2T, P, 313, 312, nullptr);

    // 6) softmax -> E ; bhT0 = (E @ H)^T
    softmax_e_h<<<40, 256, 0, stream>>>(P, b2, H, E, bhT);

    // 7) 4 belief-propagation iterations
    for (int it = 0; it < 4; ++it) {
        if (mid) {
            if (it == 0)
                adj16<1, 1><<<dim3(157, 8), 256, 0, stream>>>(
                    (const void*)raw_adj, NN, bhT, P, 314, 312, ArBf);
            else
                adj16<0, 0><<<dim3(157, 8), 256, 0, stream>>>(
                    (const void*)ArBf, KP, bhT, P, 314, 314, nullptr);
        } else {
            adj16<1, 0><<<dim3(157, 8), 256, 0, stream>>>(
                (const void*)raw_adj, NN, bhT, P, 313, 312, nullptr);
        }
        if (it == 3)
            combine_bmm<1><<<40, 256, 0, stream>>>(E, P, H, nullptr, out);
        else
            combine_bmm<0><<<40, 256, 0, stream>>>(E, P, H, bhT, nullptr);
    }
}